// Round 1
// baseline (429.532 us; speedup 1.0000x reference)
//
#include <hip/hip_runtime.h>
#include <stdint.h>

#define NR 8192
#define KD 4096
#define NC 4096

#define BM 128
#define BN 128
#define BK 32

typedef __attribute__((ext_vector_type(8))) __bf16 bf16x8;
typedef __attribute__((ext_vector_type(4))) float f32x4;
typedef unsigned short u16;
typedef unsigned int u32;

// round-to-nearest-even f32 -> bf16 bits (no NaN inputs here)
__device__ __forceinline__ u16 f2bf(float f) {
  u32 u = __builtin_bit_cast(u32, f);
  u32 r = u + 0x7FFFu + ((u >> 16) & 1u);
  return (u16)(r >> 16);
}

// sign(clip(w,-1,1)) == sign(w): +1 / -1 / 0 as bf16 bits
__device__ __forceinline__ u16 sgnbf(float f) {
  u32 u = __builtin_bit_cast(u32, f);
  u16 s = (u16)(0x3F80u | ((u >> 16) & 0x8000u));
  return (f == 0.0f) ? (u16)0 : s;
}

__global__ __launch_bounds__(256) void cvt_x_kernel(const float4* __restrict__ x,
                                                    ushort4* __restrict__ xb, int n4) {
  int i = blockIdx.x * blockDim.x + threadIdx.x;
  const int stride = gridDim.x * blockDim.x;
  for (; i < n4; i += stride) {
    float4 v = x[i];
    ushort4 o;
    o.x = f2bf(v.x); o.y = f2bf(v.y); o.z = f2bf(v.z); o.w = f2bf(v.w);
    xb[i] = o;
  }
}

__global__ __launch_bounds__(256) void cvt_w_kernel(const float4* __restrict__ w,
                                                    ushort4* __restrict__ wb, int n4) {
  int i = blockIdx.x * blockDim.x + threadIdx.x;
  const int stride = gridDim.x * blockDim.x;
  for (; i < n4; i += stride) {
    float4 v = w[i];
    ushort4 o;
    o.x = sgnbf(v.x); o.y = sgnbf(v.y); o.z = sgnbf(v.z); o.w = sgnbf(v.w);
    wb[i] = o;
  }
}

// async global->LDS, 16 bytes per lane. LDS dest must be the WAVE-UNIFORM base;
// HW writes lane i's 16B at lds_base + i*16. Global src is per-lane.
__device__ __forceinline__ void load16_to_lds(const u16* g, const u16* l) {
  auto gp = reinterpret_cast<const __attribute__((address_space(1))) void*>(
      reinterpret_cast<uintptr_t>(g));
  auto lp = reinterpret_cast<__attribute__((address_space(3))) void*>(
      static_cast<uint32_t>(reinterpret_cast<uintptr_t>(l)));
  __builtin_amdgcn_global_load_lds(gp, lp, 16, 0, 0);
}

// C = A (NRxKD, row-major bf16) * B^T (B is NCxKD row-major bf16 signs), fp32 out.
// m97 structure: 128x128 tile, BK=32, 4 waves (2x2, 64x64 each), 16x16x32 MFMA.
__global__ __launch_bounds__(256) void bingemm_kernel(const u16* __restrict__ A,
                                                      const u16* __restrict__ B,
                                                      float* __restrict__ C) {
  __shared__ __align__(16) u16 As[BM * BK];  // 8 KiB, linear row-major [128][32]
  __shared__ __align__(16) u16 Bs[BN * BK];  // 8 KiB

  const int tid = threadIdx.x;
  const int wave = tid >> 6;
  const int lane = tid & 63;

  const int bn = blockIdx.x;  // 0..31 (output col tiles)
  const int bm = blockIdx.y;  // 0..63 (output row tiles)

  const int wm = (wave >> 1) * 64;  // wave's sub-tile origin in the 128x128 tile
  const int wn = (wave & 1) * 64;

  // Staging geometry: tile = 8192 B = 2 issues x (4 waves x 64 lanes x 16 B).
  // Byte offset within a 4096 B half: wave*1024 + lane*16 -> row = off/64, col = (off%64)/2.
  const int off0 = wave * 1024 + lane * 16;
  const int r0 = off0 >> 6;         // 0..63
  const int c0 = (off0 & 63) >> 1;  // 0,8,16,24 (elements)

  const u16* gA0 = A + (size_t)(bm * BM + r0) * KD + c0;
  const u16* gA1 = A + (size_t)(bm * BM + 64 + r0) * KD + c0;
  const u16* gB0 = B + (size_t)(bn * BN + r0) * KD + c0;
  const u16* gB1 = B + (size_t)(bn * BN + 64 + r0) * KD + c0;

  // wave-uniform LDS bases (elements): issue*2048 + wave*512
  const u16* lA0 = As + wave * 512;
  const u16* lA1 = As + 2048 + wave * 512;
  const u16* lB0 = Bs + wave * 512;
  const u16* lB1 = Bs + 2048 + wave * 512;

  f32x4 acc[4][4];
  {
    const f32x4 zero = {0.0f, 0.0f, 0.0f, 0.0f};
#pragma unroll
    for (int i = 0; i < 4; ++i)
#pragma unroll
      for (int j = 0; j < 4; ++j) acc[i][j] = zero;
  }

  // MFMA A/B fragment addressing: row = lane&15 within 16-row block, k = (lane>>4)*8 contiguous
  const int frow = lane & 15;
  const int fk = (lane >> 4) * 8;

  for (int k0 = 0; k0 < KD; k0 += BK) {
    __syncthreads();  // previous iteration's ds_reads retired before overwrite
    load16_to_lds(gA0 + k0, lA0);
    load16_to_lds(gA1 + k0, lA1);
    load16_to_lds(gB0 + k0, lB0);
    load16_to_lds(gB1 + k0, lB1);
    __syncthreads();  // compiler drains vmcnt(0) before barrier -> staging visible

    bf16x8 af[4], bf[4];
#pragma unroll
    for (int mi = 0; mi < 4; ++mi)
      af[mi] = *(const bf16x8*)(As + (wm + mi * 16 + frow) * BK + fk);
#pragma unroll
    for (int ni = 0; ni < 4; ++ni)
      bf[ni] = *(const bf16x8*)(Bs + (wn + ni * 16 + frow) * BK + fk);

#pragma unroll
    for (int mi = 0; mi < 4; ++mi)
#pragma unroll
      for (int ni = 0; ni < 4; ++ni)
        acc[mi][ni] = __builtin_amdgcn_mfma_f32_16x16x32_bf16(af[mi], bf[ni], acc[mi][ni], 0, 0, 0);
  }

  // Epilogue. Verified C/D layout: col = lane&15, row = (lane>>4)*4 + reg.
  const int ccol = bn * BN + wn + (lane & 15);
  const int crow0 = bm * BM + wm + ((lane >> 4) << 2);
#pragma unroll
  for (int mi = 0; mi < 4; ++mi) {
#pragma unroll
    for (int j = 0; j < 4; ++j) {
      const int row = crow0 + mi * 16 + j;
      float* cp = C + (size_t)row * NC + ccol;
#pragma unroll
      for (int ni = 0; ni < 4; ++ni) cp[ni * 16] = acc[mi][ni][j];
    }
  }
}

// Correctness fallback if d_ws is too small for the bf16 staging buffers.
__global__ __launch_bounds__(256) void fallback_kernel(const float* __restrict__ x,
                                                       const float* __restrict__ w,
                                                       float* __restrict__ out) {
  const int col = blockIdx.x * 256 + threadIdx.x;
  const int row = blockIdx.y;
  const float* xr = x + (size_t)row * KD;
  const float* wr = w + (size_t)col * KD;
  float acc = 0.0f;
  for (int k = 0; k < KD; k += 4) {
    float4 xv = *(const float4*)&xr[k];
    float4 wv = *(const float4*)&wr[k];
    acc += (wv.x > 0.0f ? xv.x : (wv.x < 0.0f ? -xv.x : 0.0f));
    acc += (wv.y > 0.0f ? xv.y : (wv.y < 0.0f ? -xv.y : 0.0f));
    acc += (wv.z > 0.0f ? xv.z : (wv.z < 0.0f ? -xv.z : 0.0f));
    acc += (wv.w > 0.0f ? xv.w : (wv.w < 0.0f ? -xv.w : 0.0f));
  }
  out[(size_t)row * NC + col] = acc;
}

extern "C" void kernel_launch(void* const* d_in, const int* in_sizes, int n_in,
                              void* d_out, int out_size, void* d_ws, size_t ws_size,
                              hipStream_t stream) {
  const float* x = (const float*)d_in[0];  // (8192, 4096) fp32
  const float* w = (const float*)d_in[1];  // (4096, 4096) fp32
  float* out = (float*)d_out;              // (8192, 4096) fp32

  const size_t x_elems = (size_t)NR * KD;
  const size_t w_elems = (size_t)NC * KD;
  const size_t need = (x_elems + w_elems) * sizeof(u16);

  if (ws_size < need) {
    dim3 fgrid(NC / 256, NR);
    fallback_kernel<<<fgrid, 256, 0, stream>>>(x, w, out);
    return;
  }

  u16* xb = (u16*)d_ws;        // bf16 x, 64 MiB
  u16* wb = xb + x_elems;      // bf16 sign(w), 32 MiB

  cvt_x_kernel<<<2048, 256, 0, stream>>>((const float4*)x, (ushort4*)xb, (int)(x_elems / 4));
  cvt_w_kernel<<<2048, 256, 0, stream>>>((const float4*)w, (ushort4*)wb, (int)(w_elems / 4));

  dim3 grid(NC / BN, NR / BM);
  bingemm_kernel<<<grid, 256, 0, stream>>>(xb, wb, out);
}

// Round 2
// 272.363 us; speedup vs baseline: 1.5771x; 1.5771x over previous
//
#include <hip/hip_runtime.h>
#include <stdint.h>

#define M_DIM 8192
#define K_DIM 4096
#define N_DIM 4096

#define BM 256
#define BN 256
#define BK 64
#define NTILES 64  // K_DIM / BK
#define NITER 32   // NTILES / 2

typedef __attribute__((ext_vector_type(8))) __bf16 bf16x8;
typedef __attribute__((ext_vector_type(4))) float f32x4;
typedef unsigned short u16;
typedef unsigned int u32;

// round-to-nearest-even f32 -> bf16 bits (no NaN inputs here)
__device__ __forceinline__ u16 f2bf(float f) {
  u32 u = __builtin_bit_cast(u32, f);
  u32 r = u + 0x7FFFu + ((u >> 16) & 1u);
  return (u16)(r >> 16);
}

// sign(clip(w,-1,1)) == sign(w): +1 / -1 / 0 as bf16 bits
__device__ __forceinline__ u16 sgnbf(float f) {
  u32 u = __builtin_bit_cast(u32, f);
  u16 s = (u16)(0x3F80u | ((u >> 16) & 0x8000u));
  return (f == 0.0f) ? (u16)0 : s;
}

__global__ __launch_bounds__(256) void cvt_x_kernel(const float4* __restrict__ x,
                                                    ushort4* __restrict__ xb, int n4) {
  int i = blockIdx.x * blockDim.x + threadIdx.x;
  const int stride = gridDim.x * blockDim.x;
  for (; i < n4; i += stride) {
    float4 v = x[i];
    ushort4 o;
    o.x = f2bf(v.x); o.y = f2bf(v.y); o.z = f2bf(v.z); o.w = f2bf(v.w);
    xb[i] = o;
  }
}

__global__ __launch_bounds__(256) void cvt_w_kernel(const float4* __restrict__ w,
                                                    ushort4* __restrict__ wb, int n4) {
  int i = blockIdx.x * blockDim.x + threadIdx.x;
  const int stride = gridDim.x * blockDim.x;
  for (; i < n4; i += stride) {
    float4 v = w[i];
    ushort4 o;
    o.x = sgnbf(v.x); o.y = sgnbf(v.y); o.z = sgnbf(v.z); o.w = sgnbf(v.w);
    wb[i] = o;
  }
}

// async global->LDS, 16 B/lane. LDS dest is the WAVE-UNIFORM base (HW adds lane*16);
// global src is per-lane (we pre-swizzle it so the linear LDS write lands swizzled).
__device__ __forceinline__ void load16_to_lds(const u16* g, const u16* l) {
  auto gp = reinterpret_cast<const __attribute__((address_space(1))) void*>(
      reinterpret_cast<uintptr_t>(g));
  auto lp = reinterpret_cast<__attribute__((address_space(3))) void*>(
      static_cast<uint32_t>(reinterpret_cast<uintptr_t>(l)));
  __builtin_amdgcn_global_load_lds(gp, lp, 16, 0, 0);
}

__device__ __forceinline__ bf16x8 lds_read(const u16* base, int byteoff) {
  return *(const bf16x8*)((const char*)base + byteoff);
}

// ---------------------------------------------------------------------------
// 256x256 8-phase GEMM: C = A (8192x4096 bf16) * B^T (B 4096x4096 sign-bf16).
// 8 waves: wm=wave>>2 (2 M-halves of 128 rows), wn=wave&3 (4 N-slices of 64).
// LDS[buf][A=0/B=1][half][128x64], each region 16 KiB, total 128 KiB.
// Swizzle: 16B-chunk cc within a 128B row stored at cc ^ (row&7); achieved by
// inverse-permuting the global source column per lane (linear gload_lds dest).
// Phases (per K-tile pair T0=2i,T1=2i+1):
//  ph1 Q00(T0) rd a0,b0 | stage A-H0(T1)     ph5 Q00(T1) | stage A-H0(T2)
//  ph2 Q01(T0) rd b1    | stage A-H1(T1)     ph6 Q01(T1) | stage A-H1(T2)
//  ph3 Q11(T0) rd a1    | stage B-H0(T2)     ph7 Q11(T1) | stage B-H0(T3)
//  ph4 Q10(T0)          | stage B-H1(T2)*    ph8 Q10(T1) | stage B-H1(T3)*
//  (* = vmcnt(4) gate before trailing barrier; tail iteration: vmcnt(0), no stages T2/T3)
// Overwrite-safety: B regions of a buf are last read in its ph1/ph2 (or ph5/ph6),
// A regions in ph1..ph3 (ph5..ph7); every stage slot above is >= one barrier after.
// ---------------------------------------------------------------------------

#define PH_MID()                                           \
  __builtin_amdgcn_s_barrier();                            \
  asm volatile("s_waitcnt lgkmcnt(0)" ::: "memory");       \
  __builtin_amdgcn_s_setprio(1)

#define PH_END()                                           \
  __builtin_amdgcn_s_setprio(0);                           \
  __builtin_amdgcn_s_barrier()

#define STAGE(buf, mat, half, T)                                            \
  do {                                                                      \
    const u16* _s = ((mat) ? gBh[half] : gAh[half]) + (size_t)(T) * 64;     \
    const u16* _r = &lds[buf][mat][half][0] + ldsw;                         \
    load16_to_lds(_s, _r);                                                  \
    load16_to_lds(_s + (size_t)64 * K_DIM, _r + 4096);                      \
  } while (0)

#define READ_A(buf, mbase)                                                  \
  _Pragma("unroll") for (int mi = 0; mi < 4; ++mi)                          \
  _Pragma("unroll") for (int kk = 0; kk < 2; ++kk)                          \
      af[mi][kk] = lds_read(Ab[buf], ((mbase) + mi) * 2048 + rowb + ck[kk])

#define READ_B0(buf)                                                        \
  _Pragma("unroll") for (int ni = 0; ni < 2; ++ni)                          \
  _Pragma("unroll") for (int kk = 0; kk < 2; ++kk)                          \
      b0f[ni][kk] = lds_read(Bb[buf], bofN + ni * 2048 + rowb + ck[kk])

#define READ_B1(buf)                                                        \
  _Pragma("unroll") for (int ni = 0; ni < 2; ++ni)                          \
  _Pragma("unroll") for (int kk = 0; kk < 2; ++kk)                          \
      b1f[ni][kk] = lds_read(Bb[buf], bofN + (ni + 2) * 2048 + rowb + ck[kk])

#define MFMA_Q(m0, n0, BF)                                                  \
  _Pragma("unroll") for (int kk = 0; kk < 2; ++kk)                          \
  _Pragma("unroll") for (int mi = 0; mi < 4; ++mi)                          \
  _Pragma("unroll") for (int ni = 0; ni < 2; ++ni)                          \
      acc[(m0) + mi][(n0) + ni] = __builtin_amdgcn_mfma_f32_16x16x32_bf16(  \
          af[mi][kk], BF[ni][kk], acc[(m0) + mi][(n0) + ni], 0, 0, 0)

__global__ __launch_bounds__(512, 2) void bingemm_kernel(const u16* __restrict__ A,
                                                         const u16* __restrict__ B,
                                                         float* __restrict__ C) {
  __shared__ __align__(16) u16 lds[2][2][2][8192];  // 128 KiB

  const int tid = threadIdx.x;
  const int wave = tid >> 6;
  const int lane = tid & 63;

  // XCD-bijective swizzle (512 blocks % 8 XCDs == 0)
  const int orig = blockIdx.x;
  const int wgid = (orig & 7) * 64 + (orig >> 3);
  const int bm = wgid >> 4;  // 0..31
  const int bn = wgid & 15;  // 0..15

  const int wm = wave >> 2;  // wave's A half
  const int wn = wave & 3;   // wave's 64-col slice

  // ---- staging addresses (per-lane global src, pre-swizzled column) ----
  const int l3 = lane >> 3;
  const int l7 = lane & 7;
  const int csw = (l7 ^ l3) << 3;  // swizzled 16B chunk -> element offset in row
  const u16* gA = A + (size_t)(bm * 256 + wave * 8 + l3) * K_DIM + csw;
  const u16* gB = B + (size_t)(bn * 256 + wave * 8 + l3) * K_DIM + csw;
  const u16* gAh[2] = {gA, gA + (size_t)128 * K_DIM};
  const u16* gBh[2] = {gB, gB + (size_t)128 * K_DIM};
  const int ldsw = wave * 512;  // wave-uniform element offset within a region issue

  // ---- ds_read fragment addressing (swizzled) ----
  const int lane15 = lane & 15;
  const int lgrp = lane >> 4;
  const int rowb = lane15 * 128;  // byte row offset; row&7 == l7 for all frag rows
  const int ck[2] = {((lgrp ^ l7) << 4), (((4 + lgrp) ^ l7) << 4)};
  const u16* Ab[2] = {&lds[0][0][wm][0], &lds[1][0][wm][0]};
  const u16* Bb[2] = {&lds[0][1][wn >> 1][0], &lds[1][1][wn >> 1][0]};
  const int bofN = (wn & 1) * 8192;  // byte offset of wave's 64-row slice in B region

  f32x4 acc[8][4];
  {
    const f32x4 z = {0.f, 0.f, 0.f, 0.f};
#pragma unroll
    for (int i = 0; i < 8; ++i)
#pragma unroll
      for (int j = 0; j < 4; ++j) acc[i][j] = z;
  }
  bf16x8 af[4][2], b0f[2][2], b1f[2][2];

  // ---- prologue: T0 fully + T1's B halves; leave T1-B (4 loads) in flight ----
  STAGE(0, 1, 0, 0);
  STAGE(0, 1, 1, 0);
  STAGE(0, 0, 0, 0);
  STAGE(0, 0, 1, 0);
  STAGE(1, 1, 0, 1);
  STAGE(1, 1, 1, 1);
  asm volatile("s_waitcnt vmcnt(4)" ::: "memory");
  __builtin_amdgcn_s_barrier();

  for (int i = 0; i < NITER; ++i) {
    const int T1 = 2 * i + 1, T2 = 2 * i + 2, T3 = 2 * i + 3;
    const bool nl = (i < NITER - 1);

    // ph1: Q00(T0)
    READ_A(0, 0);
    READ_B0(0);
    STAGE(1, 0, 0, T1);
    PH_MID();
    MFMA_Q(0, 0, b0f);
    PH_END();

    // ph2: Q01(T0)
    READ_B1(0);
    STAGE(1, 0, 1, T1);
    PH_MID();
    MFMA_Q(0, 2, b1f);
    PH_END();

    // ph3: Q11(T0)
    READ_A(0, 4);
    if (nl) STAGE(0, 1, 0, T2);
    PH_MID();
    MFMA_Q(4, 2, b1f);
    PH_END();

    // ph4: Q10(T0) + gate (all of T1 must be landed before ph5 reads)
    if (nl) STAGE(0, 1, 1, T2);
    PH_MID();
    MFMA_Q(4, 0, b0f);
    __builtin_amdgcn_s_setprio(0);
    if (nl) asm volatile("s_waitcnt vmcnt(4)" ::: "memory");
    else    asm volatile("s_waitcnt vmcnt(0)" ::: "memory");
    __builtin_amdgcn_s_barrier();

    // ph5: Q00(T1)
    READ_A(1, 0);
    READ_B0(1);
    if (nl) STAGE(0, 0, 0, T2);
    PH_MID();
    MFMA_Q(0, 0, b0f);
    PH_END();

    // ph6: Q01(T1)
    READ_B1(1);
    if (nl) STAGE(0, 0, 1, T2);
    PH_MID();
    MFMA_Q(0, 2, b1f);
    PH_END();

    // ph7: Q11(T1)
    READ_A(1, 4);
    if (nl) STAGE(1, 1, 0, T3);
    PH_MID();
    MFMA_Q(4, 2, b1f);
    PH_END();

    // ph8: Q10(T1) + gate (all of T2 landed before next ph1 reads)
    if (nl) STAGE(1, 1, 1, T3);
    PH_MID();
    MFMA_Q(4, 0, b0f);
    __builtin_amdgcn_s_setprio(0);
    if (nl) asm volatile("s_waitcnt vmcnt(4)" ::: "memory");
    else    asm volatile("s_waitcnt vmcnt(0)" ::: "memory");
    __builtin_amdgcn_s_barrier();
  }

  // ---- epilogue: verified C/D layout col=lane&15, row=(lane>>4)*4+reg ----
  const int ccol = bn * 256 + wn * 64 + lane15;
  const int crow0 = bm * 256 + wm * 128 + (lgrp << 2);
#pragma unroll
  for (int mi = 0; mi < 8; ++mi) {
#pragma unroll
    for (int j = 0; j < 4; ++j) {
      float* cp = C + (size_t)(crow0 + mi * 16 + j) * N_DIM + ccol;
#pragma unroll
      for (int ni = 0; ni < 4; ++ni) cp[ni * 16] = acc[mi][ni][j];
    }
  }
}

// Correctness fallback if d_ws is too small for the bf16 staging buffers.
__global__ __launch_bounds__(256) void fallback_kernel(const float* __restrict__ x,
                                                       const float* __restrict__ w,
                                                       float* __restrict__ out) {
  const int col = blockIdx.x * 256 + threadIdx.x;
  const int row = blockIdx.y;
  const float* xr = x + (size_t)row * K_DIM;
  const float* wr = w + (size_t)col * K_DIM;
  float acc = 0.0f;
  for (int k = 0; k < K_DIM; k += 4) {
    float4 xv = *(const float4*)&xr[k];
    float4 wv = *(const float4*)&wr[k];
    acc += (wv.x > 0.0f ? xv.x : (wv.x < 0.0f ? -xv.x : 0.0f));
    acc += (wv.y > 0.0f ? xv.y : (wv.y < 0.0f ? -xv.y : 0.0f));
    acc += (wv.z > 0.0f ? xv.z : (wv.z < 0.0f ? -xv.z : 0.0f));
    acc += (wv.w > 0.0f ? xv.w : (wv.w < 0.0f ? -xv.w : 0.0f));
  }
  out[(size_t)row * N_DIM + col] = acc;
}

extern "C" void kernel_launch(void* const* d_in, const int* in_sizes, int n_in,
                              void* d_out, int out_size, void* d_ws, size_t ws_size,
                              hipStream_t stream) {
  const float* x = (const float*)d_in[0];  // (8192, 4096) fp32
  const float* w = (const float*)d_in[1];  // (4096, 4096) fp32
  float* out = (float*)d_out;              // (8192, 4096) fp32

  const size_t x_elems = (size_t)M_DIM * K_DIM;
  const size_t w_elems = (size_t)N_DIM * K_DIM;
  const size_t need = (x_elems + w_elems) * sizeof(u16);

  if (ws_size < need) {
    dim3 fgrid(N_DIM / 256, M_DIM);
    fallback_kernel<<<fgrid, 256, 0, stream>>>(x, w, out);
    return;
  }

  u16* xb = (u16*)d_ws;    // bf16 x, 64 MiB
  u16* wb = xb + x_elems;  // bf16 sign(w), 32 MiB

  cvt_x_kernel<<<2048, 256, 0, stream>>>((const float4*)x, (ushort4*)xb, (int)(x_elems / 4));
  cvt_w_kernel<<<2048, 256, 0, stream>>>((const float4*)w, (ushort4*)wb, (int)(w_elems / 4));

  bingemm_kernel<<<(M_DIM / BM) * (N_DIM / BN), 512, 0, stream>>>(xb, wb, out);
}

// Round 3
// 176.223 us; speedup vs baseline: 2.4374x; 1.5456x over previous
//
#include <hip/hip_runtime.h>
#include <stdint.h>

#define M_DIM 8192
#define K_DIM 4096
#define N_DIM 4096

#define BM 256
#define BN 256
#define BKB 128   // K-bytes (=elements) per tile, i8
#define NTILES 32 // K_DIM / BKB
#define NITER 16  // NTILES / 2

typedef __attribute__((ext_vector_type(4))) int i32x4;
typedef unsigned char u8;
typedef unsigned int u32;

// ---------------- prepass: quantize x to per-row i8, w to sign i8 ----------------

__device__ __forceinline__ signed char sgn8(float f) {
  return (f > 0.0f) ? (signed char)1 : ((f < 0.0f) ? (signed char)-1 : (signed char)0);
}

// one block per row: rowmax -> scale -> quantize 4096 floats to i8
__global__ __launch_bounds__(256) void cvt_x_i8(const float* __restrict__ x,
                                                signed char* __restrict__ xq,
                                                float* __restrict__ scales) {
  const int row = blockIdx.x;
  const float4* xr = (const float4*)(x + (size_t)row * K_DIM);
  const int tid = threadIdx.x;

  float4 v[4];
#pragma unroll
  for (int k = 0; k < 4; ++k) v[k] = xr[tid * 4 + k];

  float m = 0.0f;
#pragma unroll
  for (int k = 0; k < 4; ++k) {
    m = fmaxf(m, fmaxf(fmaxf(fabsf(v[k].x), fabsf(v[k].y)),
                       fmaxf(fabsf(v[k].z), fabsf(v[k].w))));
  }
#pragma unroll
  for (int off = 32; off; off >>= 1) m = fmaxf(m, __shfl_xor(m, off));

  __shared__ float wmax[4];
  if ((tid & 63) == 0) wmax[tid >> 6] = m;
  __syncthreads();
  m = fmaxf(fmaxf(wmax[0], wmax[1]), fmaxf(wmax[2], wmax[3]));
  m = fmaxf(m, 1e-30f);

  const float inv = 127.0f / m;
  if (tid == 0) scales[row] = m / 127.0f;

  signed char q[16] __attribute__((aligned(16)));
#pragma unroll
  for (int k = 0; k < 4; ++k) {
    const float* p = (const float*)&v[k];
#pragma unroll
    for (int j = 0; j < 4; ++j) {
      float t = fminf(fmaxf(p[j] * inv, -127.0f), 127.0f);
      q[k * 4 + j] = (signed char)__float2int_rn(t);
    }
  }
  *(int4*)(xq + (size_t)row * K_DIM + tid * 16) = *(const int4*)q;
}

__global__ __launch_bounds__(256) void cvt_w_i8(const float4* __restrict__ w,
                                                int4* __restrict__ wq) {
  const int i = blockIdx.x * blockDim.x + threadIdx.x;  // 16 floats / thread
  signed char q[16] __attribute__((aligned(16)));
#pragma unroll
  for (int k = 0; k < 4; ++k) {
    float4 v = w[i * 4 + k];
    q[k * 4 + 0] = sgn8(v.x);
    q[k * 4 + 1] = sgn8(v.y);
    q[k * 4 + 2] = sgn8(v.z);
    q[k * 4 + 3] = sgn8(v.w);
  }
  wq[i] = *(const int4*)q;
}

// ---------------- GEMM ----------------

// async global->LDS, 16 B/lane. LDS dest is the WAVE-UNIFORM base (HW adds lane*16);
// global src is per-lane (pre-swizzled so the linear LDS write lands swizzled).
__device__ __forceinline__ void load16_to_lds(const u8* g, const u8* l) {
  auto gp = reinterpret_cast<const __attribute__((address_space(1))) void*>(
      reinterpret_cast<uintptr_t>(g));
  auto lp = reinterpret_cast<__attribute__((address_space(3))) void*>(
      static_cast<uint32_t>(reinterpret_cast<uintptr_t>(l)));
  __builtin_amdgcn_global_load_lds(gp, lp, 16, 0, 0);
}

__device__ __forceinline__ i32x4 lds_read(const u8* base, int byteoff) {
  return *(const i32x4*)(base + byteoff);
}

// 256x256 8-phase i8 GEMM: C = s_row * (Xq (8192x4096 i8) * Wq^T (4096x4096 sign-i8)).
// Identical byte-geometry to the verified bf16 template (rows are 128 B either way):
// 8 waves (2M x 4N), LDS[buf][A/B][half][128x128B] = 128 KiB, chunk^(row&7) swizzle,
// counted vmcnt(4) gates at ph4/ph8, K-tile = 128 i8, mfma_i32_16x16x64_i8.
// Overwrite-safety / in-flight accounting identical to round-2 (same issue counts).

#define PH_MID()                                           \
  __builtin_amdgcn_s_barrier();                            \
  asm volatile("s_waitcnt lgkmcnt(0)" ::: "memory");       \
  __builtin_amdgcn_s_setprio(1)

#define PH_END()                                           \
  __builtin_amdgcn_s_setprio(0);                           \
  __builtin_amdgcn_s_barrier()

#define STAGE(buf, mat, half, T)                                            \
  do {                                                                      \
    const u8* _s = ((mat) ? gBh[half] : gAh[half]) + (size_t)(T) * BKB;     \
    const u8* _r = &lds[buf][mat][half][0] + ldsw;                          \
    load16_to_lds(_s, _r);                                                  \
    load16_to_lds(_s + (size_t)64 * K_DIM, _r + 8192);                      \
  } while (0)

#define READ_A(buf, mbase)                                                  \
  _Pragma("unroll") for (int mi = 0; mi < 4; ++mi)                          \
  _Pragma("unroll") for (int kk = 0; kk < 2; ++kk)                          \
      af[mi][kk] = lds_read(Ab[buf], ((mbase) + mi) * 2048 + rowb + ck[kk])

#define READ_B0(buf)                                                        \
  _Pragma("unroll") for (int ni = 0; ni < 2; ++ni)                          \
  _Pragma("unroll") for (int kk = 0; kk < 2; ++kk)                          \
      b0f[ni][kk] = lds_read(Bb[buf], bofN + ni * 2048 + rowb + ck[kk])

#define READ_B1(buf)                                                        \
  _Pragma("unroll") for (int ni = 0; ni < 2; ++ni)                          \
  _Pragma("unroll") for (int kk = 0; kk < 2; ++kk)                          \
      b1f[ni][kk] = lds_read(Bb[buf], bofN + (ni + 2) * 2048 + rowb + ck[kk])

#define MFMA_Q(m0, n0, BF)                                                  \
  _Pragma("unroll") for (int kk = 0; kk < 2; ++kk)                          \
  _Pragma("unroll") for (int mi = 0; mi < 4; ++mi)                          \
  _Pragma("unroll") for (int ni = 0; ni < 2; ++ni)                          \
      acc[(m0) + mi][(n0) + ni] = __builtin_amdgcn_mfma_i32_16x16x64_i8(    \
          af[mi][kk], BF[ni][kk], acc[(m0) + mi][(n0) + ni], 0, 0, 0)

__global__ __launch_bounds__(512, 2) void bingemm_kernel(const u8* __restrict__ A,
                                                         const u8* __restrict__ B,
                                                         const float* __restrict__ S,
                                                         float* __restrict__ C) {
  __shared__ __align__(16) u8 lds[2][2][2][16384];  // 128 KiB

  const int tid = threadIdx.x;
  const int wave = tid >> 6;
  const int lane = tid & 63;

  // XCD-bijective swizzle (512 blocks % 8 XCDs == 0)
  const int orig = blockIdx.x;
  const int wgid = (orig & 7) * 64 + (orig >> 3);
  const int bm = wgid >> 4;  // 0..31
  const int bn = wgid & 15;  // 0..15

  const int wm = wave >> 2;  // wave's A half
  const int wn = wave & 3;   // wave's 64-col slice

  // ---- staging addresses (per-lane global src, pre-swizzled 16B chunk) ----
  const int l3 = lane >> 3;
  const int l7 = lane & 7;
  const int csw = (l7 ^ l3) << 4;  // swizzled chunk -> byte offset in 128B row
  const u8* gA = A + (size_t)(bm * 256 + wave * 8 + l3) * K_DIM + csw;
  const u8* gB = B + (size_t)(bn * 256 + wave * 8 + l3) * K_DIM + csw;
  const u8* gAh[2] = {gA, gA + (size_t)128 * K_DIM};
  const u8* gBh[2] = {gB, gB + (size_t)128 * K_DIM};
  const int ldsw = wave * 1024;  // wave-uniform byte offset within a region issue

  // ---- ds_read fragment addressing (swizzled) ----
  const int lane15 = lane & 15;
  const int lgrp = lane >> 4;
  const int rowb = lane15 * 128;  // byte row offset; row&7 == lane&7 for frag rows
  const int ck[2] = {((lgrp ^ l7) << 4), (((4 + lgrp) ^ l7) << 4)};
  const u8* Ab[2] = {&lds[0][0][wm][0], &lds[1][0][wm][0]};
  const u8* Bb[2] = {&lds[0][1][wn >> 1][0], &lds[1][1][wn >> 1][0]};
  const int bofN = (wn & 1) * 8192;  // byte offset of wave's 64-row slice in B region

  i32x4 acc[8][4];
  {
    const i32x4 z = {0, 0, 0, 0};
#pragma unroll
    for (int i = 0; i < 8; ++i)
#pragma unroll
      for (int j = 0; j < 4; ++j) acc[i][j] = z;
  }
  i32x4 af[4][2], b0f[2][2], b1f[2][2];

  // ---- prologue: T0 fully + T1's B halves; leave T1-B (4 loads) in flight ----
  STAGE(0, 1, 0, 0);
  STAGE(0, 1, 1, 0);
  STAGE(0, 0, 0, 0);
  STAGE(0, 0, 1, 0);
  STAGE(1, 1, 0, 1);
  STAGE(1, 1, 1, 1);
  asm volatile("s_waitcnt vmcnt(4)" ::: "memory");
  __builtin_amdgcn_s_barrier();

  for (int i = 0; i < NITER; ++i) {
    const int T1 = 2 * i + 1, T2 = 2 * i + 2, T3 = 2 * i + 3;
    const bool nl = (i < NITER - 1);

    // ph1: Q00(T0)
    READ_A(0, 0);
    READ_B0(0);
    STAGE(1, 0, 0, T1);
    PH_MID();
    MFMA_Q(0, 0, b0f);
    PH_END();

    // ph2: Q01(T0)
    READ_B1(0);
    STAGE(1, 0, 1, T1);
    PH_MID();
    MFMA_Q(0, 2, b1f);
    PH_END();

    // ph3: Q11(T0)
    READ_A(0, 4);
    if (nl) STAGE(0, 1, 0, T2);
    PH_MID();
    MFMA_Q(4, 2, b1f);
    PH_END();

    // ph4: Q10(T0) + gate (all of T1 landed before ph5 reads)
    if (nl) STAGE(0, 1, 1, T2);
    PH_MID();
    MFMA_Q(4, 0, b0f);
    __builtin_amdgcn_s_setprio(0);
    if (nl) asm volatile("s_waitcnt vmcnt(4)" ::: "memory");
    else    asm volatile("s_waitcnt vmcnt(0)" ::: "memory");
    __builtin_amdgcn_s_barrier();

    // ph5: Q00(T1)
    READ_A(1, 0);
    READ_B0(1);
    if (nl) STAGE(0, 0, 0, T2);
    PH_MID();
    MFMA_Q(0, 0, b0f);
    PH_END();

    // ph6: Q01(T1)
    READ_B1(1);
    if (nl) STAGE(0, 0, 1, T2);
    PH_MID();
    MFMA_Q(0, 2, b1f);
    PH_END();

    // ph7: Q11(T1)
    READ_A(1, 4);
    if (nl) STAGE(1, 1, 0, T3);
    PH_MID();
    MFMA_Q(4, 2, b1f);
    PH_END();

    // ph8: Q10(T1) + gate (all of T2 landed before next ph1 reads)
    if (nl) STAGE(1, 1, 1, T3);
    PH_MID();
    MFMA_Q(4, 0, b0f);
    __builtin_amdgcn_s_setprio(0);
    if (nl) asm volatile("s_waitcnt vmcnt(4)" ::: "memory");
    else    asm volatile("s_waitcnt vmcnt(0)" ::: "memory");
    __builtin_amdgcn_s_barrier();
  }

  // ---- epilogue: C/D layout col=lane&15, row=(lane>>4)*4+reg; dequant by s_row ----
  const int ccol = bn * 256 + wn * 64 + lane15;
  const int crow0 = bm * 256 + wm * 128 + (lgrp << 2);
#pragma unroll
  for (int mi = 0; mi < 8; ++mi) {
#pragma unroll
    for (int j = 0; j < 4; ++j) {
      const int row = crow0 + mi * 16 + j;
      const float s = S[row];
      float* cp = C + (size_t)row * N_DIM + ccol;
#pragma unroll
      for (int ni = 0; ni < 4; ++ni) cp[ni * 16] = s * (float)acc[mi][ni][j];
    }
  }
}

// Correctness fallback if d_ws is too small for the i8 staging buffers.
__global__ __launch_bounds__(256) void fallback_kernel(const float* __restrict__ x,
                                                       const float* __restrict__ w,
                                                       float* __restrict__ out) {
  const int col = blockIdx.x * 256 + threadIdx.x;
  const int row = blockIdx.y;
  const float* xr = x + (size_t)row * K_DIM;
  const float* wr = w + (size_t)col * K_DIM;
  float acc = 0.0f;
  for (int k = 0; k < K_DIM; k += 4) {
    float4 xv = *(const float4*)&xr[k];
    float4 wv = *(const float4*)&wr[k];
    acc += (wv.x > 0.0f ? xv.x : (wv.x < 0.0f ? -xv.x : 0.0f));
    acc += (wv.y > 0.0f ? xv.y : (wv.y < 0.0f ? -xv.y : 0.0f));
    acc += (wv.z > 0.0f ? xv.z : (wv.z < 0.0f ? -xv.z : 0.0f));
    acc += (wv.w > 0.0f ? xv.w : (wv.w < 0.0f ? -xv.w : 0.0f));
  }
  out[(size_t)row * N_DIM + col] = acc;
}

extern "C" void kernel_launch(void* const* d_in, const int* in_sizes, int n_in,
                              void* d_out, int out_size, void* d_ws, size_t ws_size,
                              hipStream_t stream) {
  const float* x = (const float*)d_in[0];  // (8192, 4096) fp32
  const float* w = (const float*)d_in[1];  // (4096, 4096) fp32
  float* out = (float*)d_out;              // (8192, 4096) fp32

  const size_t x_elems = (size_t)M_DIM * K_DIM;
  const size_t w_elems = (size_t)N_DIM * K_DIM;
  const size_t need = x_elems + w_elems + (size_t)M_DIM * sizeof(float);

  if (ws_size < need) {
    dim3 fgrid(N_DIM / 256, M_DIM);
    fallback_kernel<<<fgrid, 256, 0, stream>>>(x, w, out);
    return;
  }

  signed char* xq = (signed char*)d_ws;   // 32 MiB
  signed char* wq = xq + x_elems;         // 16 MiB
  float* scales = (float*)(wq + w_elems); // 32 KiB

  cvt_x_i8<<<M_DIM, 256, 0, stream>>>(x, xq, scales);
  cvt_w_i8<<<(int)(w_elems / 16 / 256), 256, 0, stream>>>((const float4*)w, (int4*)wq);

  bingemm_kernel<<<(M_DIM / BM) * (N_DIM / BN), 512, 0, stream>>>(
      (const u8*)xq, (const u8*)wq, scales, out);
}